// Round 2
// baseline (123.832 us; speedup 1.0000x reference)
//
#include <hip/hip_runtime.h>
#include <hip/hip_cooperative_groups.h>

namespace cg = cooperative_groups;

// Problem constants (fixed by setup_inputs): N=65536 tokens, K=8, E=64 experts.
#define TOTAL   524288            // N*K flattened assignments
#define NEXP    64
#define TOPK    8
#define GSIZE   256               // blocks (1 per CU; cooperative co-resident)
#define BLOCK   256               // threads per block = 4 waves
#define NWAVE   4
#define VBLK    (GSIZE * NWAVE)   // 1024 virtual blocks, one per wave
#define WCHUNK  (TOTAL / VBLK)    // 512 elements per wave
#define WROUNDS (WCHUNK / 64)     // 8 rounds of 64 lanes

__global__ __launch_bounds__(BLOCK) void fused_kernel(
        const float* __restrict__ scores,
        const int*   __restrict__ idx,
        int*         __restrict__ counts,      // [VBLK][NEXP] in d_ws
        float*       __restrict__ out_scores,
        float*       __restrict__ out_tok,
        float*       __restrict__ out_cnt) {
    const int tid  = threadIdx.x;
    const int b    = blockIdx.x;
    const int lane = tid & 63;
    const int wave = tid >> 6;
    const int vb   = b * NWAVE + wave;          // this wave's virtual block id
    const unsigned long long ltmask = (1ULL << lane) - 1ULL;

    __shared__ int hist[NWAVE][NEXP];           // per-wave expert counts -> later reused as "running"
    __shared__ int part_pre[NWAVE][NEXP];
    __shared__ int part_tot[NWAVE][NEXP];
    __shared__ int totals[NEXP];
    __shared__ int exoff[NWAVE][NEXP];

    // ---------------- Phase 1: per-wave histogram (ballot-based, no atomics) ----
    hist[wave][lane] = 0;                       // wave-local init (64 lanes cover NEXP)
    const int base = vb * WCHUNK;

    int   myE[WROUNDS];
    float myS[WROUNDS];
    unsigned long long myM[WROUNDS];

#pragma unroll
    for (int r = 0; r < WROUNDS; r++) {
        const int i = base + r * 64 + lane;     // coalesced
        const int   e = idx[i];
        myE[r] = e;
        myS[r] = scores[i];
        // mask of same-expert lanes in this wave (E=64 -> 6 ballots)
        unsigned long long m = ~0ULL;
#pragma unroll
        for (int bit = 0; bit < 6; bit++) {
            const unsigned long long bb = __ballot((e >> bit) & 1);
            m &= ((e >> bit) & 1) ? bb : ~bb;
        }
        myM[r] = m;
        const int leader = __ffsll((long long)m) - 1;
        if (lane == leader) hist[wave][e] += __popcll(m);   // leader-only RMW, wave-serial
    }
    // publish per-virtual-block counts
    counts[vb * NEXP + lane] = hist[wave][lane];

    cg::this_grid().sync();                     // device-scope: all counts visible

    // ---------------- Phase 2a: offsets --------------------------------------
    // Each thread: expert = lane, scans a quarter of the virtual blocks.
    {
        int pre = 0, tot = 0;
        const int vb0 = b * NWAVE;              // my block's first virtual block
        const int q0  = wave * (VBLK / NWAVE);
#pragma unroll 4
        for (int q = 0; q < VBLK / NWAVE; q++) {
            const int vbb = q0 + q;
            const int c   = counts[vbb * NEXP + lane];
            tot += c;
            pre += (vbb < vb0) ? c : 0;
        }
        part_pre[wave][lane] = pre;
        part_tot[wave][lane] = tot;
    }
    __syncthreads();
    if (tid < NEXP) {
        const int pre = part_pre[0][tid] + part_pre[1][tid] + part_pre[2][tid] + part_pre[3][tid];
        const int tot = part_tot[0][tid] + part_tot[1][tid] + part_tot[2][tid] + part_tot[3][tid];
        totals[tid]      = tot;
        part_pre[0][tid] = pre;                 // reuse slot 0 as block-level prefix
        if (b == 0) out_cnt[tid] = (float)tot;  // num_tokens_per_expert (float32 output)
    }
    __syncthreads();
    if (tid == 0) {                             // exclusive scan over 64 experts
        int acc = 0;
        for (int e = 0; e < NEXP; e++) { const int t = totals[e]; totals[e] = acc; acc += t; }
    }
    __syncthreads();
    {                                           // per-wave start offset per expert
        int off = totals[lane] + part_pre[0][lane];
        for (int w2 = 0; w2 < wave; w2++) off += hist[w2][lane];  // cross-wave read (behind barriers)
        exoff[wave][lane] = off;
    }
    __syncthreads();                            // all cross-wave hist reads done
    hist[wave][lane] = 0;                       // reuse as per-wave running counter

    // ---------------- Phase 2b: stable scatter (barrier-free rounds) ---------
#pragma unroll
    for (int r = 0; r < WROUNDS; r++) {
        const int   e = myE[r];
        const float s = myS[r];
        const unsigned long long m = myM[r];
        const int inwave = __popcll(m & ltmask);
        const int run    = hist[wave][e];       // pre-round running (all lanes read)
        const int pos    = exoff[wave][e] + run + inwave;
        out_scores[pos] = s;
        out_tok[pos]    = (float)((base + r * 64 + lane) >> 3);  // /TOPK, exact in fp32
        __builtin_amdgcn_wave_barrier();        // keep read-before-write order
        const int leader = __ffsll((long long)m) - 1;
        if (lane == leader) hist[wave][e] = run + __popcll(m);
        __builtin_amdgcn_wave_barrier();
    }
}

extern "C" void kernel_launch(void* const* d_in, const int* in_sizes, int n_in,
                              void* d_out, int out_size, void* d_ws, size_t ws_size,
                              hipStream_t stream) {
    const float* top_scores = (const float*)d_in[0];
    const int*   sel_idx    = (const int*)d_in[1];
    float*       out        = (float*)d_out;
    int*         counts     = (int*)d_ws;       // VBLK*NEXP ints = 256 KB

    // d_out layout: [scores_sorted (TOTAL)] [token_idx_sorted (TOTAL)] [counts (NEXP)]
    float* out_scores = out;
    float* out_tok    = out + TOTAL;
    float* out_cnt    = out + 2 * TOTAL;

    void* args[] = { (void*)&top_scores, (void*)&sel_idx, (void*)&counts,
                     (void*)&out_scores, (void*)&out_tok, (void*)&out_cnt };
    hipLaunchCooperativeKernel((void*)fused_kernel, dim3(GSIZE), dim3(BLOCK),
                               args, 0, stream);
}

// Round 3
// 73.040 us; speedup vs baseline: 1.6954x; 1.6954x over previous
//
#include <hip/hip_runtime.h>

// Problem constants (fixed by setup_inputs): N=65536 tokens, K=8, E=64 experts.
#define TOTAL   524288            // N*K flattened assignments
#define NEXP    64
#define TOPK    8
#define GSIZE   256               // blocks
#define BLOCK   256               // threads = 4 waves
#define NWAVE   4
#define CHUNK   (TOTAL / GSIZE)   // 2048 elements per block
#define WCHUNK  (CHUNK / NWAVE)   // 512 per wave
#define WROUNDS (WCHUNK / 64)     // 8 rounds of 64 lanes

// ---------------- Kernel A: per-block expert histogram (ballot-based) -------
__global__ __launch_bounds__(BLOCK) void hist_kernel(const int* __restrict__ idx,
                                                     int* __restrict__ counts) {
    __shared__ int hist[NWAVE][NEXP];
    const int tid = threadIdx.x, lane = tid & 63, wave = tid >> 6;
    hist[wave][lane] = 0;
    const int base = blockIdx.x * CHUNK + wave * WCHUNK;
#pragma unroll
    for (int r = 0; r < WROUNDS; r++) {
        const int e = idx[base + r * 64 + lane];        // coalesced
        unsigned long long m = ~0ULL;                   // same-expert lane mask
#pragma unroll
        for (int bit = 0; bit < 6; bit++) {
            const unsigned long long bb = __ballot((e >> bit) & 1);
            m &= ((e >> bit) & 1) ? bb : ~bb;
        }
        const int leader = __ffsll((long long)m) - 1;
        if (lane == leader) hist[wave][e] += __popcll(m);  // distinct e per leader
    }
    __syncthreads();
    if (tid < NEXP)
        counts[blockIdx.x * NEXP + tid] =
            hist[0][tid] + hist[1][tid] + hist[2][tid] + hist[3][tid];
}

// ---------------- Kernel B: offsets + stable scatter ------------------------
__global__ __launch_bounds__(BLOCK) void scatter_kernel(
        const float* __restrict__ scores,
        const int*   __restrict__ idx,
        const int*   __restrict__ counts,
        float*       __restrict__ out_scores,
        float*       __restrict__ out_tok,
        float*       __restrict__ out_cnt) {
    __shared__ int hist[NWAVE][NEXP];       // per-wave expert counts
    __shared__ int part_pre[NWAVE][NEXP];   // partial prefix (blocks < b)
    __shared__ int part_tot[NWAVE][NEXP];   // partial totals
    __shared__ int exscan_pre[NEXP];        // expert ex-scan + this block's prefix
    __shared__ int exoff[NWAVE][NEXP];      // final per-wave expert start
    __shared__ int run[NWAVE][NEXP];        // running count within wave

    const int tid = threadIdx.x, lane = tid & 63, wave = tid >> 6, b = blockIdx.x;
    const unsigned long long ltmask = (1ULL << lane) - 1ULL;

    // --- counts scan: expert = lane, quarter of blocks = wave (64 indep loads) ---
    int pre = 0, tot = 0;
    {
        const int bb0 = wave * (GSIZE / NWAVE);
#pragma unroll 16
        for (int q = 0; q < GSIZE / NWAVE; q++) {
            const int bb = bb0 + q;
            const int c  = counts[bb * NEXP + lane];    // lane-coalesced rows
            tot += c;
            pre += (bb < b) ? c : 0;
        }
    }
    part_pre[wave][lane] = pre;
    part_tot[wave][lane] = tot;

    // --- per-wave element loads + same-expert masks + wave histogram ---
    hist[wave][lane] = 0;
    run[wave][lane]  = 0;
    const int base = b * CHUNK + wave * WCHUNK;
    int                myE[WROUNDS];
    float              myS[WROUNDS];
    unsigned long long myM[WROUNDS];
#pragma unroll
    for (int r = 0; r < WROUNDS; r++) {
        const int i = base + r * 64 + lane;
        const int e = idx[i];
        myE[r] = e;
        myS[r] = scores[i];
        unsigned long long m = ~0ULL;
#pragma unroll
        for (int bit = 0; bit < 6; bit++) {
            const unsigned long long bb = __ballot((e >> bit) & 1);
            m &= ((e >> bit) & 1) ? bb : ~bb;
        }
        myM[r] = m;
        const int leader = __ffsll((long long)m) - 1;
        if (lane == leader) hist[wave][e] += __popcll(m);
    }
    __syncthreads();

    // --- combine partials + expert exclusive scan (wave 0, shfl-based) ---
    if (wave == 0) {
        const int p = part_pre[0][lane] + part_pre[1][lane] +
                      part_pre[2][lane] + part_pre[3][lane];
        const int t = part_tot[0][lane] + part_tot[1][lane] +
                      part_tot[2][lane] + part_tot[3][lane];
        if (b == 0) out_cnt[lane] = (float)t;   // num_tokens_per_expert (fp32)
        int inc = t;                            // 64-lane inclusive scan
#pragma unroll
        for (int d = 1; d < 64; d <<= 1) {
            const int v = __shfl_up(inc, d, 64);
            if (lane >= d) inc += v;
        }
        exscan_pre[lane] = (inc - t) + p;       // exclusive scan + block prefix
    }
    __syncthreads();

    // --- per-wave expert start offsets ---
    {
        int off = exscan_pre[lane];
        for (int w = 0; w < wave; w++) off += hist[w][lane];
        exoff[wave][lane] = off;
    }
    __syncthreads();

    // --- stable scatter: zero block barriers, wave-lockstep ordering ---
#pragma unroll
    for (int r = 0; r < WROUNDS; r++) {
        const int e = myE[r];
        const unsigned long long m = myM[r];
        const int inwave = __popcll(m & ltmask);
        const int rn     = run[wave][e];
        const int pos    = exoff[wave][e] + rn + inwave;
        out_scores[pos] = myS[r];
        out_tok[pos]    = (float)((base + r * 64 + lane) >> 3);  // /TOPK exact in fp32
        __builtin_amdgcn_wave_barrier();
        const int leader = __ffsll((long long)m) - 1;
        if (lane == leader) run[wave][e] = rn + __popcll(m);
        __builtin_amdgcn_wave_barrier();
    }
}

extern "C" void kernel_launch(void* const* d_in, const int* in_sizes, int n_in,
                              void* d_out, int out_size, void* d_ws, size_t ws_size,
                              hipStream_t stream) {
    const float* top_scores = (const float*)d_in[0];
    const int*   sel_idx    = (const int*)d_in[1];
    float*       out        = (float*)d_out;
    int*         counts     = (int*)d_ws;   // GSIZE*NEXP ints = 64 KB

    // d_out layout: [scores_sorted (TOTAL)] [token_idx_sorted (TOTAL)] [counts (NEXP)]
    float* out_scores = out;
    float* out_tok    = out + TOTAL;
    float* out_cnt    = out + 2 * TOTAL;

    hist_kernel<<<GSIZE, BLOCK, 0, stream>>>(sel_idx, counts);
    scatter_kernel<<<GSIZE, BLOCK, 0, stream>>>(top_scores, sel_idx, counts,
                                                out_scores, out_tok, out_cnt);
}